// Round 4
// baseline (539.243 us; speedup 1.0000x reference)
//
#include <hip/hip_runtime.h>

// Self-attention B=4, S=4096, D=1024, fp32 in/out.
// R5 base (528.2 µs verified): 128² mfma_core for proj/scores/pv.
// R8: gemm_scores ported to 256²-tile / 8-wave / BK=64 4-phase schedule with
// counted vmcnt (T3+T4), setprio (T5), K-half-major LDS + 2-way-max XOR
// swizzle (T2-equivalent, race-free staging derivation in comments).
// R9: resubmission of R8 (broker failed twice; kernel never ran). Full paper
// re-audit done: swizzle round-trip, WAR/RAW windows, vmcnt counts, barrier
// uniformity, VGPR budget — all verified by hand. No source change.
// proj_qkv / gemm_pv / cvt_all unchanged (attribution discipline).

typedef unsigned short u16;
typedef __attribute__((ext_vector_type(8))) short bf16x8;
typedef __attribute__((ext_vector_type(4))) float f32x4;

__device__ __forceinline__ float bf2f(u16 h) {
    unsigned int x = ((unsigned int)h) << 16;
    float f;
    __builtin_memcpy(&f, &x, 4);
    return f;
}

__device__ __forceinline__ u16 f2bf(float f) {
    unsigned int x;
    __builtin_memcpy(&x, &f, 4);
    unsigned int r = (x + 0x7FFFu + ((x >> 16) & 1u)) >> 16;  // RNE
    return (u16)r;
}

__device__ __forceinline__ void load16_lds(const u16* g, u16* l) {
    __builtin_amdgcn_global_load_lds(
        (const __attribute__((address_space(1))) void*)g,
        (__attribute__((address_space(3))) void*)l, 16, 0, 0);
}

// ---- fused fp32 -> bf16 convert (x, Wq, Wk, Wv) + zero L, one dispatch ----
__global__ __launch_bounds__(256) void cvt_all(
    const float* __restrict__ x, const float* __restrict__ wq,
    const float* __restrict__ wk, const float* __restrict__ wv,
    u16* __restrict__ xo, u16* __restrict__ qo, u16* __restrict__ ko,
    u16* __restrict__ vo, float* __restrict__ L) {
    int i = blockIdx.x * 256 + threadIdx.x;
    if (i >= 4980736) {  // last 16 blocks: zero L (16384 floats)
        ((float4*)L)[i - 4980736] = (float4){0.f, 0.f, 0.f, 0.f};
        return;
    }
    const float* src;
    u16* dst;
    int idx;
    if (i < 4194304) {
        src = x; dst = xo; idx = i;
    } else {
        int j = i - 4194304;
        int sel = j >> 18;
        idx = j & 262143;
        src = (sel == 0) ? wq : (sel == 1) ? wk : wv;
        dst = (sel == 0) ? qo : (sel == 1) ? ko : vo;
    }
    float4 f = ((const float4*)src)[idx];
    ushort4 o;
    o.x = f2bf(f.x); o.y = f2bf(f.y); o.z = f2bf(f.z); o.w = f2bf(f.w);
    ((ushort4*)dst)[idx] = o;
}

// ---------------- shared MFMA core: 128x128, BK=64, 4 waves 2x2 ------------
// (verified R5 core — used by proj_qkv, gemm_pv, fallbacks)
__device__ __forceinline__ void mfma_core(
    const u16* __restrict__ A, const u16* __restrict__ B, int K, int ldA,
    int ldB, size_t rowA0, size_t rowB0, u16* As, u16* Bs, f32x4 acc[4][4]) {
    const int t = threadIdx.x;
    const int lane = t & 63;
    const int wave = t >> 6;
    const int wm = (wave >> 1) * 64;
    const int wn = (wave & 1) * 64;
    const int lm = lane & 15;
    const int qd = lane >> 4;
    const int kx = lm & 7;
    const int rl = lane >> 3;                 // staging row within 8-row call
    const int swz = ((lane & 7) ^ rl) << 3;   // swizzled source chunk (elems)

#pragma unroll
    for (int i = 0; i < 4; ++i)
#pragma unroll
        for (int j = 0; j < 4; ++j) acc[i][j] = (f32x4){0.f, 0.f, 0.f, 0.f};

    const u16* ga = A + (rowA0 + (size_t)(wave * 32 + rl)) * (size_t)ldA + swz;
    const u16* gb = B + (rowB0 + (size_t)(wave * 32 + rl)) * (size_t)ldB + swz;
    u16* la = As + wave * 2048;
    u16* lb = Bs + wave * 2048;

    for (int kb = 0; kb < K; kb += 64) {
#pragma unroll
        for (int p = 0; p < 4; ++p) {
            load16_lds(ga + (size_t)(p * 8) * ldA + kb, la + p * 512);
            load16_lds(gb + (size_t)(p * 8) * ldB + kb, lb + p * 512);
        }
        __syncthreads();
#pragma unroll
        for (int k0 = 0; k0 < 64; k0 += 32) {
            const int q0 = k0 >> 3;  // chunk base: 0 or 4
            const int cofs = (((q0 + qd) ^ kx) << 3);
            bf16x8 a[4], b[4];
#pragma unroll
            for (int i = 0; i < 4; ++i) {
                a[i] = *(const bf16x8*)(As + (wm + i * 16 + lm) * 64 + cofs);
                b[i] = *(const bf16x8*)(Bs + (wn + i * 16 + lm) * 64 + cofs);
            }
#pragma unroll
            for (int i = 0; i < 4; ++i)
#pragma unroll
                for (int j = 0; j < 4; ++j)
                    acc[i][j] = __builtin_amdgcn_mfma_f32_16x16x32_bf16(
                        a[i], b[j], acc[i][j], 0, 0, 0);
        }
        __syncthreads();
    }
}

// ---------------- fused QKV projection (unchanged) ----------------
__global__ __launch_bounds__(256, 4) void proj_qkv(
    const u16* __restrict__ x, const u16* __restrict__ w0,
    const u16* __restrict__ w1, const u16* __restrict__ w2,
    const float* __restrict__ b0, const float* __restrict__ b1,
    const float* __restrict__ b2, u16* __restrict__ Qb, u16* __restrict__ Kb,
    u16* __restrict__ Vt) {
    __shared__ __align__(16) u16 As[128 * 64];
    __shared__ __align__(16) u16 Bs[128 * 64];
    const int z = blockIdx.z;
    const u16* W = (z == 0) ? w0 : (z == 1) ? w1 : w2;
    const float* bias = (z == 0) ? b0 : (z == 1) ? b1 : b2;

    const size_t rowA0 = (size_t)blockIdx.y * 128;
    const size_t rowB0 = (size_t)blockIdx.x * 128;
    f32x4 acc[4][4];
    mfma_core(x, W, 1024, 1024, 1024, rowA0, rowB0, As, Bs, acc);

    const int lane = threadIdx.x & 63;
    const int wave = threadIdx.x >> 6;
    const int wm = (wave >> 1) * 64;
    const int wn = (wave & 1) * 64;
    const int lm = lane & 15;
    const int qd = lane >> 4;

#pragma unroll
    for (int i = 0; i < 4; ++i) {
        const int r0 = (int)rowA0 + wm + i * 16 + qd * 4;
#pragma unroll
        for (int j = 0; j < 4; ++j) {
            const int col = (int)rowB0 + wn + j * 16 + lm;
            const float bv = bias[col];
            if (z < 2) {
                u16* C = z ? Kb : Qb;
#pragma unroll
                for (int r = 0; r < 4; ++r)
                    C[(size_t)(r0 + r) * 1024 + col] = f2bf(acc[i][j][r] + bv);
            } else {
                const int batch = r0 >> 12;
                const int s0 = r0 & 4095;
                ushort4 o;
                o.x = f2bf(acc[i][j][0] + bv);
                o.y = f2bf(acc[i][j][1] + bv);
                o.z = f2bf(acc[i][j][2] + bv);
                o.w = f2bf(acc[i][j][3] + bv);
                *(ushort4*)(Vt + (size_t)batch * 4194304 +
                            (size_t)col * 4096 + s0) = o;
            }
        }
    }
}

// ======== scores 256²: P' = exp(QKt/32) bf16, L[row] += row-sums ==========
// 8 waves (2 row-halves × 4 col-quarters), BK=64, 4 phases/K-step.
// LDS per buffer: A[ks][256][32], B[ks][256][32]; 2 buffers = 128 KiB.
// Stage unit = one K-half of A or B (16 KiB = 2 gload_lds/thread).
//   unit issue lag: A/B-K0(s) at step s-2 phases 3/4 (region dead after ph2);
//                   A/B-K1(s) at step s-1 phases 1/2 (buffer idle).
//   waits: vmcnt(8) at phase-2 end (covers ph3 reads) and phase-4 end
//   (covers next step ph1 reads); tail drains 8→4→0. Never 0 in steady state.
// Chunk swizzle: position = chunk ^ ((row>>1)&3)  (≤2-way bank alias = free);
// source pre-swizzled so gload_lds's linear lane-order lands swizzled.
__global__ __launch_bounds__(512, 2) void gemm_scores256(
    const u16* __restrict__ Qb, const u16* __restrict__ Kb,
    u16* __restrict__ SP, float* __restrict__ L) {
    extern __shared__ __align__(16) u16 sm[];  // A: [0,32768), B: [32768,65536)
    const size_t z = blockIdx.z;
    const u16* A = Qb + z * 4194304;
    const u16* B = Kb + z * 4194304;
    u16* C = SP + z * 16777216;
    const int rowA0 = blockIdx.x * 256;  // row-block
    const int rowB0 = blockIdx.y * 256;  // col-block

    const int t = threadIdx.x;
    const int l = t & 63;
    const int w = t >> 6;            // wave 0..7
    const int wr = w >> 2;           // row half 0..1  (rows wr*128..+127)
    const int wc = w & 3;            // col quarter    (cols wc*64..+63)
    const int lm = l & 15;
    const int qd = l >> 4;
    const int rsw = (lm >> 1) & 3;                 // read swizzle
    const int srow = l >> 2;                       // staging row-in-sliver
    const int csw = (l & 3) ^ ((l >> 3) & 3);      // staging source chunk
    const int roff = (qd ^ rsw) * 8;               // read chunk offset (elems)

    f32x4 acc[8][4];
#pragma unroll
    for (int i = 0; i < 8; ++i)
#pragma unroll
        for (int j = 0; j < 4; ++j) acc[i][j] = (f32x4){0.f, 0.f, 0.f, 0.f};

    // stage one K-half unit: M=0 A / 1 B; K-step s; K-half ks; buffer bs.
    auto STAGE = [&](int M, int s, int ks, int bs) {
        const u16* G = M ? B : A;
        const int r0 = M ? rowB0 : rowA0;
        u16* lb = sm + M * 32768 + bs * 16384 + ks * 8192 + w * 512;
        const u16* g = G + (size_t)(r0 + w * 16 + srow) * 1024 +
                       (s * 64 + ks * 32 + csw * 8);
        load16_lds(g, lb);
        load16_lds(g + (size_t)128 * 1024, lb + 4096);
    };

    // ---- prologue: step0 all 4 units + step1 K0 units (12 loads/thread)
    STAGE(0, 0, 0, 0); STAGE(1, 0, 0, 0);
    STAGE(0, 0, 1, 0); STAGE(1, 0, 1, 0);
    STAGE(0, 1, 0, 1); STAGE(1, 1, 0, 1);
    asm volatile("s_waitcnt vmcnt(8)" ::: "memory");  // step0 K0 landed
    asm volatile("s_barrier" ::: "memory");
    __builtin_amdgcn_sched_barrier(0);

    const int NS = 16;  // K=1024 / BK=64
#pragma unroll 2
    for (int s = 0; s < NS; ++s) {
        const int cur = s & 1;
        const u16* As_ = sm + cur * 16384;
        const u16* Bs_ = sm + 32768 + cur * 16384;
        bf16x8 a[4], b[4];

        // ---- phase 1: (ks=0, qm=0) — read a(qm0,ks0)+b(ks0); stage A-K1(s+1)
#pragma unroll
        for (int m = 0; m < 4; ++m)
            a[m] = *(const bf16x8*)(As_ + (wr * 128 + m * 16 + lm) * 32 + roff);
#pragma unroll
        for (int n = 0; n < 4; ++n)
            b[n] = *(const bf16x8*)(Bs_ + (wc * 64 + n * 16 + lm) * 32 + roff);
        if (s + 1 < NS) STAGE(0, s + 1, 1, (s + 1) & 1);
        asm volatile("s_barrier" ::: "memory");
        __builtin_amdgcn_sched_barrier(0);
        __builtin_amdgcn_s_setprio(1);
#pragma unroll
        for (int m = 0; m < 4; ++m)
#pragma unroll
            for (int n = 0; n < 4; ++n)
                acc[m][n] = __builtin_amdgcn_mfma_f32_16x16x32_bf16(
                    a[m], b[n], acc[m][n], 0, 0, 0);
        __builtin_amdgcn_s_setprio(0);
        __builtin_amdgcn_sched_barrier(0);
        asm volatile("s_barrier" ::: "memory");
        __builtin_amdgcn_sched_barrier(0);

        // ---- phase 2: (ks=0, qm=1) — read a(qm1,ks0), reuse b; stage B-K1(s+1)
#pragma unroll
        for (int m = 0; m < 4; ++m)
            a[m] = *(const bf16x8*)(As_ + (wr * 128 + 64 + m * 16 + lm) * 32 + roff);
        if (s + 1 < NS) STAGE(1, s + 1, 1, (s + 1) & 1);
        if (s < NS - 1) asm volatile("s_waitcnt vmcnt(8)" ::: "memory");
        else            asm volatile("s_waitcnt vmcnt(0)" ::: "memory");
        asm volatile("s_barrier" ::: "memory");
        __builtin_amdgcn_sched_barrier(0);
        __builtin_amdgcn_s_setprio(1);
#pragma unroll
        for (int m = 0; m < 4; ++m)
#pragma unroll
            for (int n = 0; n < 4; ++n)
                acc[4 + m][n] = __builtin_amdgcn_mfma_f32_16x16x32_bf16(
                    a[m], b[n], acc[4 + m][n], 0, 0, 0);
        __builtin_amdgcn_s_setprio(0);
        __builtin_amdgcn_sched_barrier(0);
        asm volatile("s_barrier" ::: "memory");
        __builtin_amdgcn_sched_barrier(0);

        // ---- phase 3: (ks=1, qm=0) — read a(qm0,ks1)+b(ks1); stage A-K0(s+2)
#pragma unroll
        for (int m = 0; m < 4; ++m)
            a[m] = *(const bf16x8*)(As_ + 8192 + (wr * 128 + m * 16 + lm) * 32 + roff);
#pragma unroll
        for (int n = 0; n < 4; ++n)
            b[n] = *(const bf16x8*)(Bs_ + 8192 + (wc * 64 + n * 16 + lm) * 32 + roff);
        if (s + 2 < NS) STAGE(0, s + 2, 0, s & 1);
        asm volatile("s_barrier" ::: "memory");
        __builtin_amdgcn_sched_barrier(0);
        __builtin_amdgcn_s_setprio(1);
#pragma unroll
        for (int m = 0; m < 4; ++m)
#pragma unroll
            for (int n = 0; n < 4; ++n)
                acc[m][n] = __builtin_amdgcn_mfma_f32_16x16x32_bf16(
                    a[m], b[n], acc[m][n], 0, 0, 0);
        __builtin_amdgcn_s_setprio(0);
        __builtin_amdgcn_sched_barrier(0);
        asm volatile("s_barrier" ::: "memory");
        __builtin_amdgcn_sched_barrier(0);

        // ---- phase 4: (ks=1, qm=1) — read a(qm1,ks1), reuse b; stage B-K0(s+2)
#pragma unroll
        for (int m = 0; m < 4; ++m)
            a[m] = *(const bf16x8*)(As_ + 8192 + (wr * 128 + 64 + m * 16 + lm) * 32 + roff);
        if (s + 2 < NS) STAGE(1, s + 2, 0, s & 1);
        if (s < NS - 2)       asm volatile("s_waitcnt vmcnt(8)" ::: "memory");
        else if (s == NS - 2) asm volatile("s_waitcnt vmcnt(4)" ::: "memory");
        else                  asm volatile("s_waitcnt vmcnt(0)" ::: "memory");
        asm volatile("s_barrier" ::: "memory");
        __builtin_amdgcn_sched_barrier(0);
        __builtin_amdgcn_s_setprio(1);
#pragma unroll
        for (int m = 0; m < 4; ++m)
#pragma unroll
            for (int n = 0; n < 4; ++n)
                acc[4 + m][n] = __builtin_amdgcn_mfma_f32_16x16x32_bf16(
                    a[m], b[n], acc[4 + m][n], 0, 0, 0);
        __builtin_amdgcn_s_setprio(0);
        __builtin_amdgcn_sched_barrier(0);
        asm volatile("s_barrier" ::: "memory");
        __builtin_amdgcn_sched_barrier(0);
    }

    // ---- epilogue: exp, store bf16, row-sum partials -> LDS -> atomics
    float* Ls = (float*)sm;  // [256][4]; bufs dead (vmcnt drained at s=NS-1)
#pragma unroll
    for (int i = 0; i < 8; ++i) {
        const int rl0 = wr * 128 + i * 16 + qd * 4;  // local row base
        float part[4] = {0.f, 0.f, 0.f, 0.f};
#pragma unroll
        for (int n = 0; n < 4; ++n) {
            const int col = rowB0 + wc * 64 + n * 16 + lm;
            u16 o[4];
#pragma unroll
            for (int r = 0; r < 4; ++r) {
                float e = __expf(acc[i][n][r] * 0.03125f);
                o[r] = f2bf(e);
                part[r] += e;
            }
#pragma unroll
            for (int r = 0; r < 4; ++r)
                C[(size_t)(rowA0 + rl0 + r) * 4096 + col] = o[r];
        }
#pragma unroll
        for (int r = 0; r < 4; ++r) {
#pragma unroll
            for (int o = 8; o >= 1; o >>= 1) part[r] += __shfl_xor(part[r], o);
        }
        if (lm == 0) {
#pragma unroll
            for (int r = 0; r < 4; ++r) Ls[(rl0 + r) * 4 + wc] = part[r];
        }
    }
    __syncthreads();
    if (t < 256)
        atomicAdd(L + z * 4096 + rowA0 + t,
                  Ls[t * 4] + Ls[t * 4 + 1] + Ls[t * 4 + 2] + Ls[t * 4 + 3]);
}

// ------- PV: O = (P' Vt) / L -> fp32 (unchanged) --------------
__global__ __launch_bounds__(256, 4) void gemm_pv(
    const u16* __restrict__ SP, const u16* __restrict__ Vt,
    float* __restrict__ out, const float* __restrict__ L) {
    __shared__ __align__(16) u16 As[128 * 64];
    __shared__ __align__(16) u16 Bs[128 * 64];
    const size_t z = blockIdx.z;
    const u16* A = SP + z * 16777216;
    const u16* B = Vt + z * 4194304;
    float* C = out + z * 4194304;

    const size_t rowA0 = (size_t)blockIdx.x * 128;  // row-block (swizzled)
    const size_t rowB0 = (size_t)blockIdx.y * 128;
    f32x4 acc[4][4];
    mfma_core(A, B, 4096, 4096, 4096, rowA0, rowB0, As, Bs, acc);

    // stage 1/L for this block's 128 rows in (now free) As
    float* Lsh = (float*)As;
    const int t = threadIdx.x;
    if (t < 128) Lsh[t] = 1.0f / L[z * 4096 + rowA0 + t];
    __syncthreads();

    const int lane = t & 63;
    const int wave = t >> 6;
    const int wm = (wave >> 1) * 64;
    const int wn = (wave & 1) * 64;
    const int lm = lane & 15;
    const int qd = lane >> 4;

#pragma unroll
    for (int i = 0; i < 4; ++i) {
        const int rl0 = wm + i * 16 + qd * 4;
        const int r0 = (int)rowA0 + rl0;
#pragma unroll
        for (int j = 0; j < 4; ++j) {
            const int col = (int)rowB0 + wn + j * 16 + lm;
#pragma unroll
            for (int r = 0; r < 4; ++r)
                C[(size_t)(r0 + r) * 1024 + col] = acc[i][j][r] * Lsh[rl0 + r];
        }
    }
}

// ---------------- fallback kernels (small-ws path) -------
template <int MODE>  // 2: bf16*scale, 3: fp32
__global__ __launch_bounds__(256, 3) void gemm_nt(
    const u16* __restrict__ A, const u16* __restrict__ B,
    void* __restrict__ Cv, int K, int ldA, int ldB, int ldC, float scale) {
    __shared__ __align__(16) u16 As[128 * 64];
    __shared__ __align__(16) u16 Bs[128 * 64];
    const size_t rowA0 = (size_t)blockIdx.y * 128;
    const size_t rowB0 = (size_t)blockIdx.x * 128;
    f32x4 acc[4][4];
    mfma_core(A, B, K, ldA, ldB, rowA0, rowB0, As, Bs, acc);

    const int lane = threadIdx.x & 63;
    const int wave = threadIdx.x >> 6;
    const int wm = (wave >> 1) * 64;
    const int wn = (wave & 1) * 64;
    const int lm = lane & 15;
    const int qd = lane >> 4;

#pragma unroll
    for (int i = 0; i < 4; ++i) {
        const int r0 = (int)rowA0 + wm + i * 16 + qd * 4;
#pragma unroll
        for (int j = 0; j < 4; ++j) {
            const int col = (int)rowB0 + wn + j * 16 + lm;
            if (MODE == 2) {
                u16* C = (u16*)Cv;
#pragma unroll
                for (int r = 0; r < 4; ++r)
                    C[(size_t)(r0 + r) * ldC + col] = f2bf(acc[i][j][r] * scale);
            } else {
                float* C = (float*)Cv;
#pragma unroll
                for (int r = 0; r < 4; ++r)
                    C[(size_t)(r0 + r) * ldC + col] = acc[i][j][r];
            }
        }
    }
}

__global__ __launch_bounds__(256) void softmax_inplace(u16* __restrict__ P) {
    u16* p = P + (size_t)blockIdx.x * 4096;
    const int t = threadIdx.x;
    const int lane = t & 63;
    const int wave = t >> 6;
    __shared__ float redmax[4];
    __shared__ float redsum[4];

    uint4 raw0 = *(const uint4*)(p + t * 8);
    uint4 raw1 = *(const uint4*)(p + 2048 + t * 8);
    float v[16];
    {
        const u16* h0 = (const u16*)&raw0;
        const u16* h1 = (const u16*)&raw1;
#pragma unroll
        for (int i = 0; i < 8; ++i) v[i] = bf2f(h0[i]);
#pragma unroll
        for (int i = 0; i < 8; ++i) v[8 + i] = bf2f(h1[i]);
    }
    float m = v[0];
#pragma unroll
    for (int i = 1; i < 16; ++i) m = fmaxf(m, v[i]);
#pragma unroll
    for (int o = 32; o >= 1; o >>= 1) m = fmaxf(m, __shfl_xor(m, o));
    if (lane == 0) redmax[wave] = m;
    __syncthreads();
    m = fmaxf(fmaxf(redmax[0], redmax[1]), fmaxf(redmax[2], redmax[3]));

    float s = 0.f;
#pragma unroll
    for (int i = 0; i < 16; ++i) {
        v[i] = __expf(v[i] - m);
        s += v[i];
    }
#pragma unroll
    for (int o = 32; o >= 1; o >>= 1) s += __shfl_xor(s, o);
    if (lane == 0) redsum[wave] = s;
    __syncthreads();
    s = redsum[0] + redsum[1] + redsum[2] + redsum[3];
    const float inv = 1.0f / s;

    u16 ho[16];
#pragma unroll
    for (int i = 0; i < 16; ++i) ho[i] = f2bf(v[i] * inv);
    *(uint4*)(p + t * 8) = *(const uint4*)&ho[0];
    *(uint4*)(p + 2048 + t * 8) = *(const uint4*)&ho[8];
}

// ---------------- host launcher ----------------
extern "C" void kernel_launch(void* const* d_in, const int* in_sizes, int n_in,
                              void* d_out, int out_size, void* d_ws, size_t ws_size,
                              hipStream_t stream) {
    const float* x  = (const float*)d_in[0];
    const float* Wq = (const float*)d_in[1];
    const float* bq = (const float*)d_in[2];
    const float* Wk = (const float*)d_in[3];
    const float* bk = (const float*)d_in[4];
    const float* Wv = (const float*)d_in[5];
    const float* bv = (const float*)d_in[6];
    float* out = (float*)d_out;

    static bool attr_done = false;
    if (!attr_done) {
        hipFuncSetAttribute(reinterpret_cast<const void*>(gemm_scores256),
                            hipFuncAttributeMaxDynamicSharedMemorySize, 131072);
        attr_done = true;
    }

    const bool big = ws_size >= (size_t)234946560;  // 224 MiB + 64 KiB for L
    char* w = (char*)d_ws;
    u16 *x_bf, *wq_bf, *wk_bf, *wv_bf, *Qb, *Kb, *Vt, *SP;
    float* L = nullptr;
    if (big) {
        // SP[4] at [0,128MiB); x_bf/W alias its head (dead before SP write).
        SP    = (u16*)(w);
        x_bf  = (u16*)(w);
        wq_bf = (u16*)(w + 33554432);
        wk_bf = (u16*)(w + 35651584);
        wv_bf = (u16*)(w + 37748736);
        Qb    = (u16*)(w + 134217728);
        Kb    = (u16*)(w + 167772160);
        Vt    = (u16*)(w + 201326592);
        L     = (float*)(w + 234881024);
    } else {
        x_bf  = (u16*)(w);
        wq_bf = (u16*)(w + 33554432);
        wk_bf = (u16*)(w + 35651584);
        wv_bf = (u16*)(w + 37748736);
        Qb    = (u16*)(w + 39845888);
        Kb    = (u16*)(w + 73400320);
        Vt    = (u16*)(w + 106954752);
        SP    = (u16*)(w + 140509184);
    }

    // 1) bf16 conversions (+ L zeroing in the big path), one dispatch
    cvt_all<<<big ? 19472 : 19456, 256, 0, stream>>>(
        x, Wq, Wk, Wv, x_bf, wq_bf, wk_bf, wv_bf, L);

    // 2) fused projections: M=16384, N=1024, K=1024, z = {Q,K,V}
    proj_qkv<<<dim3(8, 128, 3), 256, 0, stream>>>(
        x_bf, wq_bf, wk_bf, wv_bf, bq, bk, bv, Qb, Kb, Vt);

    if (big) {
        // 3) P' = exp(QKt/32), L = row sums — 256² 8-wave pipelined kernel
        gemm_scores256<<<dim3(16, 16, 4), 512, 131072, stream>>>(Qb, Kb, SP, L);
        // 4) O = (P' Vt) / L
        gemm_pv<<<dim3(32, 8, 4), 256, 0, stream>>>(SP, Vt, out, L);
    } else {
        for (int b = 0; b < 4; ++b) {
            const size_t off = (size_t)b * 4194304;
            gemm_nt<2><<<dim3(32, 32, 1), 256, 0, stream>>>(
                Qb + off, Kb + off, SP, 1024, 1024, 1024, 4096, 0.03125f);
            softmax_inplace<<<4096, 256, 0, stream>>>(SP);
            gemm_nt<3><<<dim3(8, 32, 1), 256, 0, stream>>>(
                SP, Vt + off, out + off, 4096, 4096, 4096, 1024, 1.f);
        }
    }
}